// Round 10
// baseline (256.237 us; speedup 1.0000x reference)
//
#include <hip/hip_runtime.h>
#include <math.h>

typedef _Float16 h8 __attribute__((ext_vector_type(8)));
typedef float    f4v __attribute__((ext_vector_type(4)));

#define N_TRAIN 400000
#define DIMS    27
#define BQ      512
#define NCLS    11
#define KNN     3
#define NB      1000           // pass-1 blocks
#define TPB     512            // pass-1 threads (8 waves)
#define PTS_BLK 400            // points per block (1000*400 = 400000 exact)
#define PTS_SUP 80             // points per super-tile (5 ptiles)
#define NSUP    5
#define NPT     5
#define TILE_B  2048           // packed bytes per 16-pt tile: hi 1024 + lo 1024
#define SUP_B   (NPT * TILE_B) // 10240 B per supertile
#define BLK_B   (NSUP * SUP_B) // 51200 B of xpack per block
#define RAWF    2160           // floats per super-tile (80*27), fallback path
#define NC      (NB * KNN)     // candidates per query (3000)
#define SB      512            // k_scale blocks
#define RPB     784            // rows per k_scale block
#define SROWS   128
#define NCONV   6250           // k_convq train blocks (64 pts each)
#define XPACK_OFF  12355584ull // 2048-aligned
#define XPACK_SIZE 51200000ull // 25000 tiles * 2048 B
#define WS_NEED    (XPACK_OFF + XPACK_SIZE)

// ---------------- scale = max(|train|, axis=0) ----------------
__global__ __launch_bounds__(256) void k_scale(const float* __restrict__ train,
                                               unsigned* __restrict__ scale_u) {
    __shared__ float st[SROWS * DIMS];
    __shared__ float sp[243];
    int tid = threadIdx.x;
    int r0 = blockIdx.x * RPB;
    int r1 = min(r0 + RPB, N_TRAIN);
    int c  = tid % DIMS;
    int rr = tid / DIMS;
    float m = 0.f;
    for (int base = r0; base < r1; base += SROWS) {
        int cnt = min(SROWS, r1 - base);     // multiple of 4
        int tot4 = (cnt * DIMS) >> 2;
        const uint4* src4 = (const uint4*)(train + (size_t)base * DIMS);
        uint4* st4 = (uint4*)st;
        for (int i = tid; i < tot4; i += 256) st4[i] = src4[i];
        __syncthreads();
        if (tid < 243) {
            for (int r = rr; r < cnt; r += 9)
                m = fmaxf(m, fabsf(st[r * DIMS + c]));
        }
        __syncthreads();
    }
    if (tid < 243) sp[tid] = m;
    __syncthreads();
    if (tid < DIMS) {
        float v = 0.f;
#pragma unroll
        for (int g = 0; g < 9; ++g) v = fmaxf(v, sp[g * DIMS + tid]);
        atomicMax(&scale_u[tid], __float_as_uint(v)); // values >= 0: uint order == float order
    }
}

// ---------------- train preconvert + fused query prep ----------------
// Blocks 0..NCONV-1: convert 64 train points each into packed [tile][kblock][point]
// hi/lo records with -xn/2 at k=27. Blocks NCONV..NCONV+1: split-f16 query prep.
__global__ __launch_bounds__(256) void k_convq(const float* __restrict__ train,
                                               const float* __restrict__ query,
                                               const unsigned* __restrict__ scale_u,
                                               unsigned char* __restrict__ xpack,
                                               _Float16* __restrict__ Qhi,
                                               _Float16* __restrict__ Qlo) {
    int tid = threadIdx.x;
    if (blockIdx.x >= NCONV) {               // ---- query-prep blocks ----
        int q = (blockIdx.x - NCONV) * 256 + tid;
        if (q >= BQ) return;
        const float* r = query + (size_t)q * DIMS;
#pragma unroll
        for (int d = 0; d < 32; ++d) {
            _Float16 hi = (_Float16)0.f, lo = (_Float16)0.f;
            if (d < DIMS) {
                float sc = __uint_as_float(scale_u[d]);
                float inv = (sc != 0.f) ? 1.f / sc : 0.f;   // divide_no_nan
                float xs = r[d] * inv;
                hi = (_Float16)xs;
                lo = (_Float16)(xs - (float)hi);
            } else if (d == 27) {
                hi = (_Float16)1.f;          // multiplies A's -xn/2 hi+lo slots
            }
            Qhi[q * 32 + d] = hi;
            Qlo[q * 32 + d] = lo;
        }
        return;
    }
    // ---- train-convert blocks ----
    __shared__ float st[64 * DIMS];          // 6912 B
    __shared__ float s_inv[32];
    if (tid < 32) {
        float sc = __uint_as_float(scale_u[tid]);   // 0 for d>=27
        s_inv[tid] = (sc != 0.f) ? 1.f / sc : 0.f;
    }
    const uint4* src4 = (const uint4*)(train + (size_t)blockIdx.x * 64 * DIMS);
    uint4* st4 = (uint4*)st;
    if (tid < 216) { st4[tid] = src4[tid]; st4[tid + 216] = src4[tid + 216]; }
    __syncthreads();

    int p = tid >> 2, gq = tid & 3;
    float x[8]; float part = 0.f;
#pragma unroll
    for (int i = 0; i < 8; ++i) {
        int d = gq * 8 + i;
        int dc = d < DIMS ? d : (DIMS - 1);  // clamp; s_inv[d>=27]=0 zeroes value
        float v = st[p * DIMS + dc] * s_inv[d];
        x[i] = v;
        part = fmaf(v, v, part);
    }
    part += __shfl_xor(part, 1, 64);
    part += __shfl_xor(part, 2, 64);         // 4 lanes of a point all hold xn
    h8 hv, lv;
#pragma unroll
    for (int i = 0; i < 8; ++i) {
        _Float16 h = (_Float16)x[i];
        hv[i] = h;
        lv[i] = (_Float16)(x[i] - (float)h);
    }
    if (gq == 3) {                           // slot i=3 is k=27: -xn/2 split
        float tt = -0.5f * part;
        _Float16 th = (_Float16)tt;
        hv[3] = th;
        lv[3] = (_Float16)(tt - (float)th);
    }
    size_t tbase = ((size_t)blockIdx.x * 4 + (p >> 4)) * TILE_B;
    unsigned char* dst = xpack + tbase + gq * 256 + (p & 15) * 16;
    *(h8*)dst = hv;
    *(h8*)(dst + 1024) = lv;
}

// batch-max over 4 candidates (eq-select keeps earliest on ties) + branchless top-2
#define BMAX4_TOP2(A0, A1, A2, A3, G0, G1, G2, G3, B0, B1, I0, I1) do { \
    float m_ = fmaxf(fmaxf(A0, A1), fmaxf(A2, A3)); \
    int gm_ = (m_ == (A0)) ? (G0) : (m_ == (A1)) ? (G1) : (m_ == (A2)) ? (G2) : (G3); \
    bool c0_ = m_ > (B0); \
    bool c1_ = m_ > (B1); \
    B1 = c0_ ? (B0) : (c1_ ? m_ : (B1)); \
    I1 = c0_ ? (I0) : (c1_ ? gm_ : (I1)); \
    B0 = c0_ ? m_ : (B0); \
    I0 = c0_ ? gm_ : (I0); \
} while (0)

// lexicographic (key, idx) insert into ascending sorted triple — matches top_k ties
__device__ __forceinline__ void insert3(float d, int i, float* bd, int* bi) {
    if (d < bd[2] || (d == bd[2] && i < bi[2])) {
        if (d < bd[1] || (d == bd[1] && i < bi[1])) {
            bd[2] = bd[1]; bi[2] = bi[1];
            if (d < bd[0] || (d == bd[0] && i < bi[0])) {
                bd[1] = bd[0]; bi[1] = bi[0];
                bd[0] = d; bi[0] = i;
            } else { bd[1] = d; bi[1] = i; }
        } else { bd[2] = d; bi[2] = i; }
    }
}

// lexicographic insert into sorted 8
__device__ __forceinline__ void ins8(float d, int i, float* bd, int* bi) {
    if (!(d < bd[7] || (d == bd[7] && i < bi[7]))) return;
#pragma unroll
    for (int k = 7; k >= 1; --k) {
        if (d < bd[k - 1] || (d == bd[k - 1] && i < bi[k - 1])) {
            bd[k] = bd[k - 1]; bi[k] = bi[k - 1];
        } else { bd[k] = d; bi[k] = i; return; }
    }
    bd[0] = d; bi[0] = i;
}

__device__ __forceinline__ void stage16(const void* g, void* l) {
    __builtin_amdgcn_global_load_lds((const __attribute__((address_space(1))) void*)g,
                                     (__attribute__((address_space(3))) void*)l, 16, 0, 0);
}

// shared epilogue: cross-quad merge -> block top-3 per query -> [query][block] store
__device__ __forceinline__ void merge_store(float* b0, float* b1, int* i0, int* i1,
                                            int w, int l15, int quad, int g,
                                            float* cand_d, int* cand_i) {
#pragma unroll
    for (int j = 0; j < 4; ++j) {
        float kk[3] = {-b0[j], -b1[j], 3.4e38f};
        int   ii[3] = {i0[j], i1[j], 0x7fffffff};
#pragma unroll
        for (int step = 16; step <= 32; step <<= 1) {
            float od[3]; int oi[3];
#pragma unroll
            for (int k = 0; k < 3; ++k) {
                od[k] = __shfl_xor(kk[k], step, 64);
                oi[k] = __shfl_xor(ii[k], step, 64);
            }
#pragma unroll
            for (int k = 0; k < 3; ++k) insert3(od[k], oi[k], kk, ii);
        }
        if (quad == 0) {
            int qq = (w * 4 + j) * 16 + l15;
            size_t off = (size_t)qq * NC + (size_t)g * KNN;   // [query][block]
#pragma unroll
            for (int k = 0; k < KNN; ++k) { cand_d[off + k] = kk[k]; cand_i[off + k] = ii[k]; }
        }
    }
}

// ---------------- pass 1 (packed): stage xpack supertiles, pure MFMA + select ----------------
__global__ __launch_bounds__(TPB)
void k_pass1p(const unsigned char* __restrict__ xpack,
              const _Float16* __restrict__ Qhi,
              const _Float16* __restrict__ Qlo,
              float* __restrict__ cand_d,
              int* __restrict__ cand_i) {
    __shared__ __align__(16) unsigned char xb[2][SUP_B];   // 20480 B

    int tid = threadIdx.x;
    int lane = tid & 63, w = tid >> 6;
    int l15 = lane & 15, quad = lane >> 4;

    h8 bhi[4], blo[4];
#pragma unroll
    for (int j = 0; j < 4; ++j) {
        int qt = w * 4 + j;
        size_t e = (size_t)(qt * 16 + l15) * 32 + quad * 8;
        bhi[j] = *(const h8*)(Qhi + e);
        blo[j] = *(const h8*)(Qlo + e);
    }

    float b0[4], b1[4];
    int   i0[4], i1[4];
#pragma unroll
    for (int j = 0; j < 4; ++j) { b0[j] = -3.4e38f; b1[j] = -3.4e38f; i0[j] = 0x7fffffff; i1[j] = 0x7fffffff; }

    int p0 = blockIdx.x * PTS_BLK;
    const unsigned char* gbase = xpack + (size_t)blockIdx.x * BLK_B;

    {   // stage supertile 0 (640 x 16B)
        const unsigned char* gp = gbase;
        stage16(gp + tid * 16, xb[0] + tid * 16);
        if (tid < 128) stage16(gp + 8192 + tid * 16, xb[0] + 8192 + tid * 16);
    }

    for (int s = 0; s < NSUP; ++s) {
        __syncthreads();   // drains stage(s); all waves done with xb[(s+1)&1]

        if (s + 1 < NSUP) {   // stage next supertile; flies during compute(s)
            const unsigned char* gp = gbase + (size_t)(s + 1) * SUP_B;
            unsigned char* lp = xb[(s + 1) & 1];
            stage16(gp + tid * 16, lp + tid * 16);
            if (tid < 128) stage16(gp + 8192 + tid * 16, lp + 8192 + tid * 16);
        }

        const unsigned char* buf = xb[s & 1];
        for (int t = 0; t < NPT; ++t) {
            const unsigned char* basep = buf + t * TILE_B;
            h8 ahi = *(const h8*)(basep + lane * 16);       // lane-linear: conflict-free
            h8 alo = *(const h8*)(basep + 1024 + lane * 16);
            int gb = p0 + (s * NPT + t) * 16 + quad * 4;
#pragma unroll
            for (int j = 0; j < 4; ++j) {
                f4v acc = {0.f, 0.f, 0.f, 0.f};
                acc = __builtin_amdgcn_mfma_f32_16x16x32_f16(alo, bhi[j], acc, 0, 0, 0);
                acc = __builtin_amdgcn_mfma_f32_16x16x32_f16(ahi, blo[j], acc, 0, 0, 0);
                acc = __builtin_amdgcn_mfma_f32_16x16x32_f16(ahi, bhi[j], acc, 0, 0, 0);
                BMAX4_TOP2(acc[0], acc[1], acc[2], acc[3], gb, gb + 1, gb + 2, gb + 3,
                           b0[j], b1[j], i0[j], i1[j]);
            }
        }
    }
    merge_store(b0, b1, i0, i1, w, l15, quad, blockIdx.x, cand_d, cand_i);
}

// ---------------- pass 1 (fallback, inline convert; used if ws too small) ----------------
__global__ __launch_bounds__(TPB)
void k_pass1f(const float* __restrict__ train,
              const unsigned* __restrict__ scale_u,
              const _Float16* __restrict__ Qhi,
              const _Float16* __restrict__ Qlo,
              float* __restrict__ cand_d,
              int* __restrict__ cand_i) {
    __shared__ float s_inv[32];
    __shared__ __align__(16) float raw[2][RAWF];                 // 17280 B
    __shared__ __align__(16) unsigned char conv[NPT * TILE_B];   // 10240 B

    int tid = threadIdx.x;
    if (tid < 32) {
        float sc = __uint_as_float(scale_u[tid]);
        s_inv[tid] = (sc != 0.f) ? 1.f / sc : 0.f;
    }
    int lane = tid & 63, w = tid >> 6;
    int l15 = lane & 15, quad = lane >> 4;

    h8 bhi[4], blo[4];
#pragma unroll
    for (int j = 0; j < 4; ++j) {
        int qt = w * 4 + j;
        size_t e = (size_t)(qt * 16 + l15) * 32 + quad * 8;
        bhi[j] = *(const h8*)(Qhi + e);
        blo[j] = *(const h8*)(Qlo + e);
    }
    float b0[4], b1[4];
    int   i0[4], i1[4];
#pragma unroll
    for (int j = 0; j < 4; ++j) { b0[j] = -3.4e38f; b1[j] = -3.4e38f; i0[j] = 0x7fffffff; i1[j] = 0x7fffffff; }

    int p0 = blockIdx.x * PTS_BLK;
    const float* gsup = train + (size_t)p0 * DIMS;   // 400*108 % 16 == 0
    {   // stage supertile 0 (540 x 16B)
        const float* gp = gsup; float* lp = raw[0];
        stage16(gp + tid * 4, lp + tid * 4);
        if (tid < 28) stage16(gp + 2048 + tid * 4, lp + 2048 + tid * 4);
    }
    for (int s = 0; s < NSUP; ++s) {
        __syncthreads();
        const float* rw = raw[s & 1];
        if (tid < PTS_SUP * 4) {
            int p = tid >> 2, gq = tid & 3;
            float x[8]; float part = 0.f;
#pragma unroll
            for (int i = 0; i < 8; ++i) {
                int d = gq * 8 + i;
                int dc = d < DIMS ? d : (DIMS - 1);
                float v = rw[p * DIMS + dc] * s_inv[d];
                x[i] = v;
                part = fmaf(v, v, part);
            }
            part += __shfl_xor(part, 1, 64);
            part += __shfl_xor(part, 2, 64);
            h8 hv, lv;
#pragma unroll
            for (int i = 0; i < 8; ++i) {
                _Float16 h = (_Float16)x[i];
                hv[i] = h;
                lv[i] = (_Float16)(x[i] - (float)h);
            }
            if (gq == 3) {
                float tt = -0.5f * part;
                _Float16 th = (_Float16)tt;
                hv[3] = th;
                lv[3] = (_Float16)(tt - (float)th);
            }
            unsigned char* dstb = conv + (p >> 4) * TILE_B + gq * 256 + (p & 15) * 16;
            *(h8*)dstb = hv;
            *(h8*)(dstb + 1024) = lv;
        }
        __syncthreads();
        if (s + 1 < NSUP) {
            const float* gp = gsup + (size_t)(s + 1) * RAWF;
            float* lp = raw[(s + 1) & 1];
            stage16(gp + tid * 4, lp + tid * 4);
            if (tid < 28) stage16(gp + 2048 + tid * 4, lp + 2048 + tid * 4);
        }
        for (int t = 0; t < NPT; ++t) {
            const unsigned char* basep = conv + t * TILE_B;
            h8 ahi = *(const h8*)(basep + lane * 16);
            h8 alo = *(const h8*)(basep + 1024 + lane * 16);
            int gb = p0 + (s * NPT + t) * 16 + quad * 4;
#pragma unroll
            for (int j = 0; j < 4; ++j) {
                f4v acc = {0.f, 0.f, 0.f, 0.f};
                acc = __builtin_amdgcn_mfma_f32_16x16x32_f16(alo, bhi[j], acc, 0, 0, 0);
                acc = __builtin_amdgcn_mfma_f32_16x16x32_f16(ahi, blo[j], acc, 0, 0, 0);
                acc = __builtin_amdgcn_mfma_f32_16x16x32_f16(ahi, bhi[j], acc, 0, 0, 0);
                BMAX4_TOP2(acc[0], acc[1], acc[2], acc[3], gb, gb + 1, gb + 2, gb + 3,
                           b0[j], b1[j], i0[j], i1[j]);
            }
        }
    }
    merge_store(b0, b1, i0, i1, w, l15, quad, blockIdx.x, cand_d, cand_i);
}

// ---------------- pass 2: approx top-8 merge -> exact f32 refine -> vote ----------------
__global__ __launch_bounds__(64) void k_pass2(const float* __restrict__ cand_d,
                                              const int* __restrict__ cand_i,
                                              const float* __restrict__ train,
                                              const float* __restrict__ query,
                                              const unsigned* __restrict__ scale_u,
                                              const float* __restrict__ labels,
                                              float* __restrict__ out) {
    int q = blockIdx.x, lane = threadIdx.x;
    const float* cd = cand_d + (size_t)q * NC;
    const int*   ci = cand_i + (size_t)q * NC;

    float d8[8]; int i8v[8];
#pragma unroll
    for (int k = 0; k < 8; ++k) { d8[k] = 3.4e38f; i8v[k] = 0x7fffffff; }
    for (int c = lane; c < NC; c += 64) ins8(cd[c], ci[c], d8, i8v);

#pragma unroll
    for (int step = 1; step < 64; step <<= 1) {
        float od[8]; int oi[8];
#pragma unroll
        for (int k = 0; k < 8; ++k) {
            od[k] = __shfl_xor(d8[k], step, 64);
            oi[k] = __shfl_xor(i8v[k], step, 64);
        }
#pragma unroll
        for (int k = 0; k < 8; ++k) ins8(od[k], oi[k], d8, i8v);
    }
    // all lanes hold identical global approx top-8

    float inv[DIMS], qs_[DIMS], qn_ = 0.f;
#pragma unroll
    for (int d = 0; d < DIMS; ++d) {
        float sc = __uint_as_float(scale_u[d]);
        float iv = (sc != 0.f) ? 1.f / sc : 0.f;
        float v = query[(size_t)q * DIMS + d] * iv;
        inv[d] = iv; qs_[d] = v;
        qn_ = fmaf(v, v, qn_);
    }

    int myi = 0x7fffffff;
#pragma unroll
    for (int k = 0; k < 8; ++k) if (lane == k) myi = i8v[k];
    float myd2 = 3.4e38f;
    if (lane < 8) {
        const float* r = train + (size_t)myi * DIMS;
        float xnv = 0.f, dot = 0.f;
#pragma unroll
        for (int d = 0; d < DIMS; ++d) {
            float v = r[d] * inv[d];
            xnv = fmaf(v, v, xnv);
            dot = fmaf(qs_[d], v, dot);
        }
        myd2 = fmaf(-2.f, dot, qn_ + xnv);   // identical to verified R1 formula
    }

    float bd[KNN] = {3.4e38f, 3.4e38f, 3.4e38f};
    int   bi[KNN] = {0x7fffffff, 0x7fffffff, 0x7fffffff};
#pragma unroll
    for (int k = 0; k < 8; ++k) {
        float dk = __shfl(myd2, k, 64);
        int   ik = __shfl(myi, k, 64);
        insert3(dk, ik, bd, bi);
    }

    if (lane == 0) {
        float kd[KNN];
#pragma unroll
        for (int k = 0; k < KNN; ++k) kd[k] = sqrtf(fmaxf(bd[k], 0.f));
        float lab[KNN][NCLS];
#pragma unroll
        for (int k = 0; k < KNN; ++k) {
            const float* lr = labels + (size_t)bi[k] * NCLS;
#pragma unroll
            for (int c = 0; c < NCLS; ++c) lab[k][c] = lr[c];
        }
        float votes[NCLS];
#pragma unroll
        for (int c = 0; c < NCLS; ++c) votes[c] = 0.f;
#pragma unroll
        for (int k = 0; k < KNN; ++k) {
            float ks = (kd[k] == 0.f) ? 1.f : kd[k];
#pragma unroll
            for (int c = 0; c < NCLS; ++c) votes[c] += lab[k][c] / ks;
        }
        int best = 0; float bv = votes[0];
#pragma unroll
        for (int c = 1; c < NCLS; ++c) { if (votes[c] > bv) { bv = votes[c]; best = c; } }
        bool zero_hit = (kd[0] == 0.f);
#pragma unroll
        for (int k = 0; k < KNN; ++k) out[(size_t)q * KNN + k] = kd[k];
        float* ro = out + (size_t)BQ * KNN + (size_t)q * NCLS;
#pragma unroll
        for (int c = 0; c < NCLS; ++c)
            ro[c] = zero_hit ? lab[0][c] : ((c == best) ? 1.f : 0.f);
    }
}

extern "C" void kernel_launch(void* const* d_in, const int* in_sizes, int n_in,
                              void* d_out, int out_size, void* d_ws, size_t ws_size,
                              hipStream_t stream) {
    const float* query  = (const float*)d_in[0];
    const float* train  = (const float*)d_in[1];
    const float* labels = (const float*)d_in[2];
    float* out = (float*)d_out;

    // ws layout:
    //   [0)         scale_u: 32 u32 (128 B, memset 0)
    //   [128)       Qhi: 512*32 f16 (32768 B)
    //   [32896)     Qlo: 512*32 f16 (32768 B)
    //   [65664)     cand_d: 512*3000 f32 (6144000 B)
    //   [6209664)   cand_i: 512*3000 i32 (6144000 B)
    //   [12355584)  xpack: 25000 tiles * 2048 B = 51.2 MB (packed-path only)
    char* ws = (char*)d_ws;
    unsigned*      scale_u = (unsigned*)ws;
    _Float16*      Qhi = (_Float16*)(ws + 128);
    _Float16*      Qlo = (_Float16*)(ws + 32896);
    float*         cand_d = (float*)(ws + 65664);
    int*           cand_i = (int*)(ws + 6209664);
    unsigned char* xpack = (unsigned char*)(ws + XPACK_OFF);

    hipMemsetAsync(ws, 0, 128, stream);   // zero scale accumulators
    k_scale<<<SB, 256, 0, stream>>>(train, scale_u);
    k_convq<<<NCONV + 2, 256, 0, stream>>>(train, query, scale_u, xpack, Qhi, Qlo);
    if (ws_size >= WS_NEED) {
        k_pass1p<<<NB, TPB, 0, stream>>>(xpack, Qhi, Qlo, cand_d, cand_i);
    } else {
        k_pass1f<<<NB, TPB, 0, stream>>>(train, scale_u, Qhi, Qlo, cand_d, cand_i);
    }
    k_pass2<<<BQ, 64, 0, stream>>>(cand_d, cand_i, train, query, scale_u, labels, out);
}